// Round 1
// baseline (13.223 us; speedup 1.0000x reference)
//
#include <hip/hip_runtime.h>
#include <hip/hip_bf16.h>

// out[b, p, d] = mean_{j=0..7} emb[x[b, p*8 + j], d]
// B=16, T=16384, MAX_PATCH=8, D=128, VOCAB=256.
// Flattened: patches = 16*2048 = 32768; out floats = 32768*128 = 4,194,304.
// One thread per float4 of output: n4 = 1,048,576.
// 32 threads (half-wave) share one patch -> each gathered row is a coalesced
// 32 x float4 = 512B read; index loads are broadcast (same addr in half-wave).

__global__ __launch_bounds__(256) void blt_patch_mean_kernel(
    const int* __restrict__ x,        // [B*T] int32 byte ids
    const float4* __restrict__ emb4,  // [256][32] float4 view of [256][128] f32
    float4* __restrict__ out4,        // [B*Tp*32] float4 view of output
    int n4)
{
    int g = blockIdx.x * blockDim.x + threadIdx.x;
    if (g >= n4) return;

    int patch = g >> 5;   // 32 float4 per patch row (D=128)
    int col   = g & 31;   // which float4 within the row

    const int* idx = x + patch * 8;   // 8 byte-ids for this patch, 32B aligned
    int4 i0 = *reinterpret_cast<const int4*>(idx);
    int4 i1 = *reinterpret_cast<const int4*>(idx + 4);

    float4 acc = make_float4(0.f, 0.f, 0.f, 0.f);
    #define ACCUM(r) { float4 v = emb4[(r) * 32 + col];                       \
                       acc.x += v.x; acc.y += v.y; acc.z += v.z; acc.w += v.w; }
    ACCUM(i0.x); ACCUM(i0.y); ACCUM(i0.z); ACCUM(i0.w);
    ACCUM(i1.x); ACCUM(i1.y); ACCUM(i1.z); ACCUM(i1.w);
    #undef ACCUM

    const float s = 0.125f;  // 1/MAX_PATCH
    acc.x *= s; acc.y *= s; acc.z *= s; acc.w *= s;
    out4[g] = acc;
}

extern "C" void kernel_launch(void* const* d_in, const int* in_sizes, int n_in,
                              void* d_out, int out_size, void* d_ws, size_t ws_size,
                              hipStream_t stream)
{
    const int*    x    = (const int*)d_in[0];     // [16*16384]
    const float4* emb4 = (const float4*)d_in[1];  // [256*128] f32 -> [256*32] f4
    float4*       out4 = (float4*)d_out;          // [4194304] f32 -> [1048576] f4

    int n4 = out_size / 4;                        // 1,048,576
    int block = 256;
    int grid = (n4 + block - 1) / block;          // 4096
    blt_patch_mean_kernel<<<grid, block, 0, stream>>>(x, emb4, out4, n4);
}

// Round 2
// 11.671 us; speedup vs baseline: 1.1330x; 1.1330x over previous
//
#include <hip/hip_runtime.h>
#include <hip/hip_bf16.h>

// out[b, p, d] = mean_{j=0..7} emb[x[b, p*8 + j], d]
// B=16, T=16384, MAX_PATCH=8, D=128, VOCAB=256.
// Patches = 32768, out float4s = 1,048,576.
//
// R1: stage the full 256x128 fp32 table (128 KB) in LDS once per block,
// serve the 128 MB gather from LDS (~52-69 TB/s) instead of L2 (~11 TB/s
// effective at random 512B segments). 256 blocks (1/CU) x 1024 threads,
// each 32-lane group owns one patch per iteration, 4 iterations.

#define NPATCH  32768
#define TPB     1024
#define NBLK    256
#define NGROUPS ((NBLK * TPB) / 32)   // 8192 half-wave groups
#define ITERS   (NPATCH / NGROUPS)    // 4

__global__ __launch_bounds__(TPB, 1) void blt_patch_mean_lds(
    const int4* __restrict__ x4,      // [NPATCH*2] int4 view of [B*T] indices
    const float4* __restrict__ emb4,  // [256*32] float4 view of [256][128] f32
    float4* __restrict__ out4)        // [NPATCH*32] float4 view of output
{
    extern __shared__ float4 tbl[];   // 8192 float4 = 128 KB

    // Stage table: 8192 float4 / 1024 threads = 8 each, fully coalesced.
    #pragma unroll
    for (int i = 0; i < 8; ++i) {
        int k = i * TPB + threadIdx.x;
        tbl[k] = emb4[k];
    }
    __syncthreads();

    const int group0 = ((int)blockIdx.x * TPB + (int)threadIdx.x) >> 5;
    const int col    = threadIdx.x & 31;

    #pragma unroll
    for (int it = 0; it < ITERS; ++it) {
        const int p = group0 + it * NGROUPS;

        // 8 byte-ids for this patch; same addr across the 32-lane group
        // -> broadcast loads, L2-served (1 MB total across grid).
        int4 i0 = x4[p * 2];
        int4 i1 = x4[p * 2 + 1];

        float4 acc = make_float4(0.f, 0.f, 0.f, 0.f);
        #define ACCUM(r) { float4 v = tbl[(r) * 32 + col];                     \
                           acc.x += v.x; acc.y += v.y; acc.z += v.z; acc.w += v.w; }
        ACCUM(i0.x); ACCUM(i0.y); ACCUM(i0.z); ACCUM(i0.w);
        ACCUM(i1.x); ACCUM(i1.y); ACCUM(i1.z); ACCUM(i1.w);
        #undef ACCUM

        const float s = 0.125f;  // 1/MAX_PATCH
        acc.x *= s; acc.y *= s; acc.z *= s; acc.w *= s;
        out4[p * 32 + col] = acc;
    }
}

extern "C" void kernel_launch(void* const* d_in, const int* in_sizes, int n_in,
                              void* d_out, int out_size, void* d_ws, size_t ws_size,
                              hipStream_t stream)
{
    const int4*   x4   = (const int4*)d_in[0];    // [16*16384] int32 -> int4
    const float4* emb4 = (const float4*)d_in[1];  // [256*128] f32 -> float4
    float4*       out4 = (float4*)d_out;

    blt_patch_mean_lds<<<NBLK, TPB, 131072, stream>>>(x4, emb4, out4);
}